// Round 5
// baseline (449.977 us; speedup 1.0000x reference)
//
#include <hip/hip_runtime.h>

// ---------------------------------------------------------------------------
// MaskedSelfAttention, S=8192, D=256, multiplicative mask before softmax.
//   q = query@Wq^T+bq ; k = key@Wk^T+bk ; v = value@Wv^T+bv
//   h = softmax(q@k^T * mask * (1/16)) @ v ; out = h@Wo^T + bo
// Round 5: 512-thread flash blocks (8 waves x 32 q-rows, BM=256), 1 block/CU,
// triple-buffered K/V LDS (96KB) with 2-body staging slack (vmcnt(8) keeps
// mask(t+1)+stage(t+2) in flight), split-pinned XCD mapping, fixed V swizzle.
// ---------------------------------------------------------------------------

#define S 8192
#define NSPLIT 8
#define BM 256   // q-rows per block (8 waves x 32)
#define BN 32    // keys per tile
#define KSPL (S / NSPLIT)     // 1024
#define NT (KSPL / BN)        // 32 (even)

typedef unsigned short ushort_t;
typedef __attribute__((ext_vector_type(8))) __bf16 bf16x8;
typedef __attribute__((ext_vector_type(4))) float f32x4;
typedef __attribute__((ext_vector_type(4))) ushort_t ushort4_t;
typedef __attribute__((ext_vector_type(8))) ushort_t ushort8_t;
typedef __attribute__((ext_vector_type(4))) unsigned uint4_t;

typedef const __attribute__((address_space(1))) unsigned int* gas_u32;
typedef __attribute__((address_space(3))) unsigned int* las_u32;

__device__ __forceinline__ ushort_t f2bf(float f) {
  unsigned u = __builtin_bit_cast(unsigned, f);
  u += 0x7FFFu + ((u >> 16) & 1u);
  return (ushort_t)(u >> 16);
}

__device__ __forceinline__ bf16x8 pack8(f32x4 a, f32x4 b) {
  ushort8_t u;
  u[0] = f2bf(a[0]); u[1] = f2bf(a[1]); u[2] = f2bf(a[2]); u[3] = f2bf(a[3]);
  u[4] = f2bf(b[0]); u[5] = f2bf(b[1]); u[6] = f2bf(b[2]); u[7] = f2bf(b[3]);
  return __builtin_bit_cast(bf16x8, u);
}

__device__ __forceinline__ unsigned cvt_pk_bf16(float lo, float hi) {
  unsigned r;
  asm("v_cvt_pk_bf16_f32 %0, %1, %2" : "=v"(r) : "v"(lo), "v"(hi));
  return r;
}

// ---------------------------------------------------------------------------
__global__ __launch_bounds__(256) void wconv_kernel(
    const float* __restrict__ w0, const float* __restrict__ w1,
    const float* __restrict__ w2, const float* __restrict__ w3,
    ushort_t* __restrict__ o0, ushort_t* __restrict__ o1,
    ushort_t* __restrict__ o2, ushort_t* __restrict__ o3) {
  const int m = blockIdx.y;
  const float* w = (m == 0) ? w0 : (m == 1) ? w1 : (m == 2) ? w2 : w3;
  ushort_t* o = (m == 0) ? o0 : (m == 1) ? o1 : (m == 2) ? o2 : o3;
  const int idx = (blockIdx.x * 256 + threadIdx.x) * 4;
  f32x4 v = *(const f32x4*)(w + idx);
  ushort4_t p;
  p[0] = f2bf(v[0]); p[1] = f2bf(v[1]); p[2] = f2bf(v[2]); p[3] = f2bf(v[3]);
  *(ushort4_t*)(o + idx) = p;
}

// ---------------------------------------------------------------------------
// Fused QKV projection. grid (128, 4, 3). z==2 writes transposed V^T.
// ---------------------------------------------------------------------------
__global__ __launch_bounds__(256) void qkv_kernel(
    const float* __restrict__ query, const float* __restrict__ key,
    const float* __restrict__ value,
    const ushort_t* __restrict__ Wqb, const ushort_t* __restrict__ Wkb,
    const ushort_t* __restrict__ Wvb,
    const float* __restrict__ bq, const float* __restrict__ bk,
    const float* __restrict__ bv,
    ushort_t* __restrict__ qo, ushort_t* __restrict__ ko,
    ushort_t* __restrict__ vto) {
  __shared__ __align__(16) ushort_t tb[64 * 68];
  const int z = blockIdx.z;
  const float* inp = (z == 0) ? query : (z == 1) ? key : value;
  const ushort_t* Wb = (z == 0) ? Wqb : (z == 1) ? Wkb : Wvb;
  const float* bias = (z == 0) ? bq : (z == 1) ? bk : bv;

  const int tid = threadIdx.x;
  const int lane = tid & 63;
  const int w = tid >> 6;
  const int lr = lane & 15, lg = lane >> 4;
  const int brow0 = blockIdx.x * 64;
  const int row0 = brow0 + w * 16;
  const int col0 = blockIdx.y * 64;

  f32x4 acc[4] = {};
  const int arow = row0 + lr;
  const int kb = lg * 8;

  bf16x8 af[8];
#pragma unroll
  for (int ks = 0; ks < 8; ++ks) {
    const float* ap = inp + (size_t)arow * 256 + ks * 32 + kb;
    af[ks] = pack8(*(const f32x4*)ap, *(const f32x4*)(ap + 4));
  }
#pragma unroll
  for (int ks = 0; ks < 8; ++ks) {
#pragma unroll
    for (int n = 0; n < 4; ++n) {
      bf16x8 bb = *(const bf16x8*)(Wb + (size_t)(col0 + 16 * n + lr) * 256 + ks * 32 + kb);
      acc[n] = __builtin_amdgcn_mfma_f32_16x16x32_bf16(af[ks], bb, acc[n], 0, 0, 0);
    }
  }

  if (z < 2) {
    ushort_t* o = z ? ko : qo;
#pragma unroll
    for (int n = 0; n < 4; ++n) {
      const int col = col0 + 16 * n + lr;
      const float bv_ = bias[col];
      const int rbase = row0 + lg * 4;
#pragma unroll
      for (int r = 0; r < 4; ++r)
        o[(size_t)(rbase + r) * 256 + col] = f2bf(acc[n][r] + bv_);
    }
  } else {
#pragma unroll
    for (int n = 0; n < 4; ++n) {
      const int col = col0 + 16 * n + lr;
      const float bv_ = bias[col];
      const int cl = 16 * n + lr;
      const int rowl = w * 16 + lg * 4;
      ushort4_t pk;
#pragma unroll
      for (int r = 0; r < 4; ++r) pk[r] = f2bf(acc[n][r] + bv_);
      *(ushort4_t*)&tb[cl * 68 + rowl] = pk;
    }
    __syncthreads();
#pragma unroll
    for (int i = 0; i < 4; ++i) {
      int chunk = i * 256 + tid;
      int c = chunk >> 4;
      int off = (chunk & 15) * 4;
      ushort4_t v0 = *(const ushort4_t*)&tb[c * 68 + off];
      *(ushort4_t*)(vto + (size_t)(col0 + c) * S + brow0 + off) = v0;
    }
  }
}

// ---------------------------------------------------------------------------
__global__ __launch_bounds__(256) void oproj_kernel(const ushort_t* __restrict__ inp,
                                                    const ushort_t* __restrict__ Wb,
                                                    const float* __restrict__ bias,
                                                    float* __restrict__ outp) {
  const int tid = threadIdx.x;
  const int lane = tid & 63;
  const int w = tid >> 6;
  const int lr = lane & 15, lg = lane >> 4;
  const int row0 = blockIdx.x * 64 + w * 16;
  const int col0 = blockIdx.y * 64;

  f32x4 acc[4] = {};
  const int arow = row0 + lr;
  const int kb = lg * 8;
#pragma unroll
  for (int ks = 0; ks < 8; ++ks) {
    bf16x8 a = *(const bf16x8*)(inp + (size_t)arow * 256 + ks * 32 + kb);
#pragma unroll
    for (int n = 0; n < 4; ++n) {
      bf16x8 bb = *(const bf16x8*)(Wb + (size_t)(col0 + 16 * n + lr) * 256 + ks * 32 + kb);
      acc[n] = __builtin_amdgcn_mfma_f32_16x16x32_bf16(a, bb, acc[n], 0, 0, 0);
    }
  }
#pragma unroll
  for (int n = 0; n < 4; ++n) {
    const int col = col0 + 16 * n + lr;
    const float bv = bias[col];
    const int rbase = row0 + lg * 4;
#pragma unroll
    for (int r = 0; r < 4; ++r)
      outp[(size_t)(rbase + r) * 256 + col] = acc[n][r] + bv;
  }
}

// ---------------------------------------------------------------------------
// Flash attention core. Grid 256 (1-D), block 512 (8 waves x 32 q-rows).
// blockIdx.x: split = b&7 (pins split to XCD), qx = b>>3.
// Triple-buffered K/V; body t: issue mask(t+1), stage(t+2); bottom vmcnt(8)
// drains stage(t+1) (2 bodies old) keeping mask(t+1)+stage(t+2) in flight.
// ---------------------------------------------------------------------------
__global__ __launch_bounds__(512, 2) void flash_kernel(
    const ushort_t* __restrict__ qg, const ushort_t* __restrict__ kbm,
    const ushort_t* __restrict__ vtb, const float* __restrict__ mask,
    float* __restrict__ Opart, float* __restrict__ lpart) {
  __shared__ __align__(16) ushort_t lk[3][BN * 256];   // 3 x 16 KB
  __shared__ __align__(16) ushort_t lv[3][256 * BN];   // 3 x 16 KB

  const int tid = threadIdx.x;
  const int lane = tid & 63;
  const int w = tid >> 6;            // 0..7
  const int lr = lane & 15, lg = lane >> 4;
  const int b = blockIdx.x;
  const int split = b & 7;
  const int qx = b >> 3;
  const int kvbase = split * KSPL;
  const int qrow0 = qx * BM + w * 32;

  // Q fragments (B-operand): lane holds Q[q=qb*16+lr][k=ks*32+lg*8+j]
  bf16x8 qf[2][8];
#pragma unroll
  for (int qb = 0; qb < 2; ++qb)
#pragma unroll
    for (int ks = 0; ks < 8; ++ks)
      qf[qb][ks] = *(const bf16x8*)(qg + (size_t)(qrow0 + qb * 16 + lr) * 256 + ks * 32 + lg * 8);

  const float* mrow[2];
#pragma unroll
  for (int qb = 0; qb < 2; ++qb)
    mrow[qb] = mask + (size_t)(qrow0 + qb * 16 + lr) * S + lg * 4;

  f32x4 oacc[2][16] = {};
  float lsum[2] = {0.f, 0.f};
  const int vt_swz = ((lg ^ ((lr >> 1) & 3)) << 4);

  auto stage = [&](int bi, int kv0) {
#pragma unroll
    for (int it = 0; it < 2; ++it) {
      int chunk = it * 512 + tid;
      int r = chunk >> 5;
      int c = (chunk & 31) ^ (r & 7);
      const ushort_t* src = kbm + (size_t)(kv0 + r) * 256 + c * 8;
      __builtin_amdgcn_global_load_lds((gas_u32)src,
                                       (las_u32)(&lk[bi][0] + chunk * 8), 16, 0, 0);
    }
#pragma unroll
    for (int it = 0; it < 2; ++it) {
      int chunk = it * 512 + tid;
      int r = chunk >> 2;
      int c = (chunk & 3) ^ ((r >> 1) & 3);
      const ushort_t* src = vtb + (size_t)r * S + kv0 + c * 8;
      __builtin_amdgcn_global_load_lds((gas_u32)src,
                                       (las_u32)(&lv[bi][0] + chunk * 8), 16, 0, 0);
    }
  };

  f32x4 mA[2][2], mB[2][2];

  // prologue: stage(0) | mask(0)->mA | stage(1); drain stage(0) only
  stage(0, kvbase);
  __builtin_amdgcn_sched_barrier(0);
#pragma unroll
  for (int qb = 0; qb < 2; ++qb)
#pragma unroll
    for (int kb = 0; kb < 2; ++kb)
      mA[qb][kb] = __builtin_nontemporal_load((const f32x4*)(mrow[qb] + kvbase + kb * 16));
  __builtin_amdgcn_sched_barrier(0);
  stage(1, kvbase + BN);
  __builtin_amdgcn_sched_barrier(0);
  asm volatile("s_waitcnt vmcnt(8)" ::: "memory");
  __builtin_amdgcn_s_barrier();
  __builtin_amdgcn_sched_barrier(0);

  auto body = [&](int t, f32x4 (&mU)[2][2], f32x4 (&mL)[2][2]) {
    const int cur = t % 3;
    const int kvn = kvbase + ((t + 1 < NT) ? (t + 1) : (NT - 1)) * BN;
    const int kvs = kvbase + ((t + 2 < NT) ? (t + 2) : (NT - 1)) * BN;

    // (1) mask(t+1) -> mL  (4 vmem; must precede stage(t+2) in the FIFO)
#pragma unroll
    for (int qb = 0; qb < 2; ++qb)
#pragma unroll
      for (int kb = 0; kb < 2; ++kb)
        mL[qb][kb] = __builtin_nontemporal_load((const f32x4*)(mrow[qb] + kvn + kb * 16));
    __builtin_amdgcn_sched_barrier(0);

    // (2) stage(t+2)  (4 vmem)
    stage((t + 2) % 3, kvs);
    __builtin_amdgcn_sched_barrier(0);

    // (3) QK^T (swapped): sacc[qb][kb] = P^T [key=kb*16+lg*4+r][q=qb*16+lr]
    f32x4 sacc[2][2] = {};
    __builtin_amdgcn_s_setprio(1);
#pragma unroll
    for (int ks = 0; ks < 8; ++ks)
#pragma unroll
      for (int kb = 0; kb < 2; ++kb) {
        int addr = ((kb * 16 + lr) << 9) + ((((ks << 2) + lg) ^ (lr & 7)) << 4);
        bf16x8 kf = *(const bf16x8*)((const char*)&lk[cur][0] + addr);
        sacc[0][kb] = __builtin_amdgcn_mfma_f32_16x16x32_bf16(kf, qf[0][ks], sacc[0][kb], 0, 0, 0);
        sacc[1][kb] = __builtin_amdgcn_mfma_f32_16x16x32_bf16(kf, qf[1][ks], sacc[1][kb], 0, 0, 0);
      }
    __builtin_amdgcn_s_setprio(0);

    // (4) softmax numerator + bf16 pack (uses mU = mask tile t)
    unsigned pw[2][2][2];
#pragma unroll
    for (int qb = 0; qb < 2; ++qb) {
      float p[8];
#pragma unroll
      for (int kb = 0; kb < 2; ++kb)
#pragma unroll
        for (int r = 0; r < 4; ++r) {
          float pv = __builtin_amdgcn_exp2f(sacc[qb][kb][r] * (mU[qb][kb][r] * 0.09016844005556021f));
          p[kb * 4 + r] = pv;
          lsum[qb] += pv;
        }
      pw[qb][0][0] = cvt_pk_bf16(p[0], p[1]);
      pw[qb][0][1] = cvt_pk_bf16(p[2], p[3]);
      pw[qb][1][0] = cvt_pk_bf16(p[4], p[5]);
      pw[qb][1][1] = cvt_pk_bf16(p[6], p[7]);
    }

    // (5) permlane redistribution -> PV B-frag (P[k=lg*8+j][q=lr])
    bf16x8 pfrag[2];
#pragma unroll
    for (int qb = 0; qb < 2; ++qb) {
      unsigned a0 = pw[qb][0][0], a1 = pw[qb][0][1];
      unsigned b0 = pw[qb][1][0], b1 = pw[qb][1][1];
      asm("v_permlane32_swap_b32 %0, %1" : "+v"(a0), "+v"(b0));
      asm("v_permlane16_swap_b32 %0, %1" : "+v"(a0), "+v"(b0));
      asm("v_permlane32_swap_b32 %0, %1" : "+v"(a1), "+v"(b1));
      asm("v_permlane16_swap_b32 %0, %1" : "+v"(a1), "+v"(b1));
      uint4_t u = {a0, a1, b0, b1};
      pfrag[qb] = __builtin_bit_cast(bf16x8, u);
    }

    // (6) PV: O^T[d][q] += V^T[d][k] P^T[k][q]
    __builtin_amdgcn_s_setprio(1);
#pragma unroll
    for (int nd = 0; nd < 16; ++nd) {
      bf16x8 va = *(const bf16x8*)((const char*)&lv[cur][0] + nd * 1024 + lr * 64 + vt_swz);
      oacc[0][nd] = __builtin_amdgcn_mfma_f32_16x16x32_bf16(va, pfrag[0], oacc[0][nd], 0, 0, 0);
      oacc[1][nd] = __builtin_amdgcn_mfma_f32_16x16x32_bf16(va, pfrag[1], oacc[1][nd], 0, 0, 0);
    }
    __builtin_amdgcn_s_setprio(0);

    // (7) drain stage(t+1) (2 bodies old); keep mask(t+1)+stage(t+2) in flight
    asm volatile("s_waitcnt vmcnt(8)" ::: "memory");
    __builtin_amdgcn_s_barrier();
    __builtin_amdgcn_sched_barrier(0);
  };

  for (int t = 0; t < NT; t += 2) {
    body(t, mA, mB);
    body(t + 1, mB, mA);
  }

  // ---- epilogue ----
#pragma unroll
  for (int qb = 0; qb < 2; ++qb) {
    float v = lsum[qb];
    v += __shfl_xor(v, 16);
    v += __shfl_xor(v, 32);
    if (lane < 16)
      lpart[(size_t)split * S + qrow0 + qb * 16 + lr] = v;
#pragma unroll
    for (int nd = 0; nd < 16; ++nd)
      *(f32x4*)(Opart + ((size_t)split * S + qrow0 + qb * 16 + lr) * 256 + nd * 16 + lg * 4) = oacc[qb][nd];
  }
}

// ---------------------------------------------------------------------------
__global__ __launch_bounds__(256) void combine_kernel(const float* __restrict__ Opart,
                                                      const float* __restrict__ lpart,
                                                      ushort_t* __restrict__ hb) {
  const int row = blockIdx.x;
  const int d = threadIdx.x;
  float L = 0.f, acc = 0.f;
#pragma unroll
  for (int s2 = 0; s2 < NSPLIT; ++s2) {
    L += lpart[(size_t)s2 * S + row];
    acc += Opart[((size_t)s2 * S + row) * 256 + d];
  }
  hb[(size_t)row * 256 + d] = f2bf(acc / L);
}

// ---------------------------------------------------------------------------
extern "C" void kernel_launch(void* const* d_in, const int* in_sizes, int n_in,
                              void* d_out, int out_size, void* d_ws, size_t ws_size,
                              hipStream_t stream) {
  const float* query = (const float*)d_in[0];
  const float* key   = (const float*)d_in[1];
  const float* value = (const float*)d_in[2];
  const float* mask  = (const float*)d_in[3];
  const float* Wq = (const float*)d_in[4];
  const float* bq = (const float*)d_in[5];
  const float* Wk = (const float*)d_in[6];
  const float* bk = (const float*)d_in[7];
  const float* Wv = (const float*)d_in[8];
  const float* bv = (const float*)d_in[9];
  const float* Wo = (const float*)d_in[10];
  const float* bo = (const float*)d_in[11];

  char* ws = (char*)d_ws;
  ushort_t* qb  = (ushort_t*)(ws);                        // 4 MB bf16 [8192,256]
  ushort_t* kb  = (ushort_t*)(ws + ((size_t)4  << 20));   // 4 MB bf16 [8192,256]
  ushort_t* vtb = (ushort_t*)(ws + ((size_t)8  << 20));   // 4 MB bf16 [256,8192]
  ushort_t* hb  = (ushort_t*)(ws + ((size_t)12 << 20));   // 4 MB bf16 [8192,256]
  ushort_t* Wqb = (ushort_t*)(ws + ((size_t)16 << 20));                 // 4x128 KB
  ushort_t* Wkb = (ushort_t*)(ws + ((size_t)16 << 20) + (128u << 10));
  ushort_t* Wvb = (ushort_t*)(ws + ((size_t)16 << 20) + (256u << 10));
  ushort_t* Wob = (ushort_t*)(ws + ((size_t)16 << 20) + (384u << 10));
  float* lpart  = (float*)(ws + ((size_t)16 << 20) + (512u << 10));     // 256 KB
  float* Opart  = (float*)(ws + ((size_t)17 << 20));      // 8 x 8 MB

  wconv_kernel<<<dim3(64, 4), 256, 0, stream>>>(Wq, Wk, Wv, Wo, Wqb, Wkb, Wvb, Wob);

  qkv_kernel<<<dim3(S / 64, 4, 3), 256, 0, stream>>>(query, key, value,
                                                     Wqb, Wkb, Wvb, bq, bk, bv,
                                                     qb, kb, vtb);

  flash_kernel<<<dim3(256), 512, 0, stream>>>(qb, kb, vtb, mask, Opart, lpart);

  combine_kernel<<<S, 256, 0, stream>>>(Opart, lpart, hb);

  oproj_kernel<<<dim3(S / 64, 4), 256, 0, stream>>>(hb, Wob, bo, (float*)d_out);
}

// Round 6
// 449.189 us; speedup vs baseline: 1.0018x; 1.0018x over previous
//
#include <hip/hip_runtime.h>

// ---------------------------------------------------------------------------
// MaskedSelfAttention, S=8192, D=256, multiplicative mask before softmax.
//   q = query@Wq^T+bq ; k = key@Wk^T+bk ; v = value@Wv^T+bv
//   h = softmax(q@k^T * mask * (1/16)) @ v ; out = h@Wo^T + bo
// Round 6: round-5 structure with the launch-bounds fix: __launch_bounds__
// (512,1) -> 256 regs/wave (round 5's (512,2) forced a 128-reg cap and
// spilled ~1GB of scratch traffic). 8 waves x 32 q-rows, 1 block/CU,
// triple-buffered K/V LDS, 2-body staging slack, split-pinned XCD mapping.
// ---------------------------------------------------------------------------

#define S 8192
#define NSPLIT 8
#define BM 256   // q-rows per block (8 waves x 32)
#define BN 32    // keys per tile
#define KSPL (S / NSPLIT)     // 1024
#define NT (KSPL / BN)        // 32 (even)

typedef unsigned short ushort_t;
typedef __attribute__((ext_vector_type(8))) __bf16 bf16x8;
typedef __attribute__((ext_vector_type(4))) float f32x4;
typedef __attribute__((ext_vector_type(4))) ushort_t ushort4_t;
typedef __attribute__((ext_vector_type(8))) ushort_t ushort8_t;
typedef __attribute__((ext_vector_type(4))) unsigned uint4_t;

typedef const __attribute__((address_space(1))) unsigned int* gas_u32;
typedef __attribute__((address_space(3))) unsigned int* las_u32;

__device__ __forceinline__ ushort_t f2bf(float f) {
  unsigned u = __builtin_bit_cast(unsigned, f);
  u += 0x7FFFu + ((u >> 16) & 1u);
  return (ushort_t)(u >> 16);
}

__device__ __forceinline__ bf16x8 pack8(f32x4 a, f32x4 b) {
  ushort8_t u;
  u[0] = f2bf(a[0]); u[1] = f2bf(a[1]); u[2] = f2bf(a[2]); u[3] = f2bf(a[3]);
  u[4] = f2bf(b[0]); u[5] = f2bf(b[1]); u[6] = f2bf(b[2]); u[7] = f2bf(b[3]);
  return __builtin_bit_cast(bf16x8, u);
}

__device__ __forceinline__ unsigned cvt_pk_bf16(float lo, float hi) {
  unsigned r;
  asm("v_cvt_pk_bf16_f32 %0, %1, %2" : "=v"(r) : "v"(lo), "v"(hi));
  return r;
}

// ---------------------------------------------------------------------------
__global__ __launch_bounds__(256) void wconv_kernel(
    const float* __restrict__ w0, const float* __restrict__ w1,
    const float* __restrict__ w2, const float* __restrict__ w3,
    ushort_t* __restrict__ o0, ushort_t* __restrict__ o1,
    ushort_t* __restrict__ o2, ushort_t* __restrict__ o3) {
  const int m = blockIdx.y;
  const float* w = (m == 0) ? w0 : (m == 1) ? w1 : (m == 2) ? w2 : w3;
  ushort_t* o = (m == 0) ? o0 : (m == 1) ? o1 : (m == 2) ? o2 : o3;
  const int idx = (blockIdx.x * 256 + threadIdx.x) * 4;
  f32x4 v = *(const f32x4*)(w + idx);
  ushort4_t p;
  p[0] = f2bf(v[0]); p[1] = f2bf(v[1]); p[2] = f2bf(v[2]); p[3] = f2bf(v[3]);
  *(ushort4_t*)(o + idx) = p;
}

// ---------------------------------------------------------------------------
// Fused QKV projection. grid (128, 4, 3). z==2 writes transposed V^T.
// ---------------------------------------------------------------------------
__global__ __launch_bounds__(256) void qkv_kernel(
    const float* __restrict__ query, const float* __restrict__ key,
    const float* __restrict__ value,
    const ushort_t* __restrict__ Wqb, const ushort_t* __restrict__ Wkb,
    const ushort_t* __restrict__ Wvb,
    const float* __restrict__ bq, const float* __restrict__ bk,
    const float* __restrict__ bv,
    ushort_t* __restrict__ qo, ushort_t* __restrict__ ko,
    ushort_t* __restrict__ vto) {
  __shared__ __align__(16) ushort_t tb[64 * 68];
  const int z = blockIdx.z;
  const float* inp = (z == 0) ? query : (z == 1) ? key : value;
  const ushort_t* Wb = (z == 0) ? Wqb : (z == 1) ? Wkb : Wvb;
  const float* bias = (z == 0) ? bq : (z == 1) ? bk : bv;

  const int tid = threadIdx.x;
  const int lane = tid & 63;
  const int w = tid >> 6;
  const int lr = lane & 15, lg = lane >> 4;
  const int brow0 = blockIdx.x * 64;
  const int row0 = brow0 + w * 16;
  const int col0 = blockIdx.y * 64;

  f32x4 acc[4] = {};
  const int arow = row0 + lr;
  const int kb = lg * 8;

  bf16x8 af[8];
#pragma unroll
  for (int ks = 0; ks < 8; ++ks) {
    const float* ap = inp + (size_t)arow * 256 + ks * 32 + kb;
    af[ks] = pack8(*(const f32x4*)ap, *(const f32x4*)(ap + 4));
  }
#pragma unroll
  for (int ks = 0; ks < 8; ++ks) {
#pragma unroll
    for (int n = 0; n < 4; ++n) {
      bf16x8 bb = *(const bf16x8*)(Wb + (size_t)(col0 + 16 * n + lr) * 256 + ks * 32 + kb);
      acc[n] = __builtin_amdgcn_mfma_f32_16x16x32_bf16(af[ks], bb, acc[n], 0, 0, 0);
    }
  }

  if (z < 2) {
    ushort_t* o = z ? ko : qo;
#pragma unroll
    for (int n = 0; n < 4; ++n) {
      const int col = col0 + 16 * n + lr;
      const float bv_ = bias[col];
      const int rbase = row0 + lg * 4;
#pragma unroll
      for (int r = 0; r < 4; ++r)
        o[(size_t)(rbase + r) * 256 + col] = f2bf(acc[n][r] + bv_);
    }
  } else {
#pragma unroll
    for (int n = 0; n < 4; ++n) {
      const int col = col0 + 16 * n + lr;
      const float bv_ = bias[col];
      const int cl = 16 * n + lr;
      const int rowl = w * 16 + lg * 4;
      ushort4_t pk;
#pragma unroll
      for (int r = 0; r < 4; ++r) pk[r] = f2bf(acc[n][r] + bv_);
      *(ushort4_t*)&tb[cl * 68 + rowl] = pk;
    }
    __syncthreads();
#pragma unroll
    for (int i = 0; i < 4; ++i) {
      int chunk = i * 256 + tid;
      int c = chunk >> 4;
      int off = (chunk & 15) * 4;
      ushort4_t v0 = *(const ushort4_t*)&tb[c * 68 + off];
      *(ushort4_t*)(vto + (size_t)(col0 + c) * S + brow0 + off) = v0;
    }
  }
}

// ---------------------------------------------------------------------------
__global__ __launch_bounds__(256) void oproj_kernel(const ushort_t* __restrict__ inp,
                                                    const ushort_t* __restrict__ Wb,
                                                    const float* __restrict__ bias,
                                                    float* __restrict__ outp) {
  const int tid = threadIdx.x;
  const int lane = tid & 63;
  const int w = tid >> 6;
  const int lr = lane & 15, lg = lane >> 4;
  const int row0 = blockIdx.x * 64 + w * 16;
  const int col0 = blockIdx.y * 64;

  f32x4 acc[4] = {};
  const int arow = row0 + lr;
  const int kb = lg * 8;
#pragma unroll
  for (int ks = 0; ks < 8; ++ks) {
    bf16x8 a = *(const bf16x8*)(inp + (size_t)arow * 256 + ks * 32 + kb);
#pragma unroll
    for (int n = 0; n < 4; ++n) {
      bf16x8 bb = *(const bf16x8*)(Wb + (size_t)(col0 + 16 * n + lr) * 256 + ks * 32 + kb);
      acc[n] = __builtin_amdgcn_mfma_f32_16x16x32_bf16(a, bb, acc[n], 0, 0, 0);
    }
  }
#pragma unroll
  for (int n = 0; n < 4; ++n) {
    const int col = col0 + 16 * n + lr;
    const float bv = bias[col];
    const int rbase = row0 + lg * 4;
#pragma unroll
    for (int r = 0; r < 4; ++r)
      outp[(size_t)(rbase + r) * 256 + col] = acc[n][r] + bv;
  }
}

// ---------------------------------------------------------------------------
// Flash attention core. Grid 256 (1-D), block 512 (8 waves x 32 q-rows).
// blockIdx.x: split = b&7 (pins split to XCD -> K/V L2-resident), qx = b>>3.
// Triple-buffered K/V; body t: issue mask(t+1), stage(t+2); bottom vmcnt(8)
// drains stage(t+1) (2 bodies old) keeping mask(t+1)+stage(t+2) in flight.
// __launch_bounds__(512,1): 1 block/CU min -> 256 regs/wave, NO SPILL.
// ---------------------------------------------------------------------------
__global__ __launch_bounds__(512, 1) void flash_kernel(
    const ushort_t* __restrict__ qg, const ushort_t* __restrict__ kbm,
    const ushort_t* __restrict__ vtb, const float* __restrict__ mask,
    float* __restrict__ Opart, float* __restrict__ lpart) {
  __shared__ __align__(16) ushort_t lk[3][BN * 256];   // 3 x 16 KB
  __shared__ __align__(16) ushort_t lv[3][256 * BN];   // 3 x 16 KB

  const int tid = threadIdx.x;
  const int lane = tid & 63;
  const int w = tid >> 6;            // 0..7
  const int lr = lane & 15, lg = lane >> 4;
  const int b = blockIdx.x;
  const int split = b & 7;
  const int qx = b >> 3;
  const int kvbase = split * KSPL;
  const int qrow0 = qx * BM + w * 32;

  // Q fragments (B-operand): lane holds Q[q=qb*16+lr][k=ks*32+lg*8+j]
  bf16x8 qf[2][8];
#pragma unroll
  for (int qb = 0; qb < 2; ++qb)
#pragma unroll
    for (int ks = 0; ks < 8; ++ks)
      qf[qb][ks] = *(const bf16x8*)(qg + (size_t)(qrow0 + qb * 16 + lr) * 256 + ks * 32 + lg * 8);

  const float* mrow[2];
#pragma unroll
  for (int qb = 0; qb < 2; ++qb)
    mrow[qb] = mask + (size_t)(qrow0 + qb * 16 + lr) * S + lg * 4;

  f32x4 oacc[2][16] = {};
  float lsum[2] = {0.f, 0.f};
  const int vt_swz = ((lg ^ ((lr >> 1) & 3)) << 4);

  auto stage = [&](int bi, int kv0) {
#pragma unroll
    for (int it = 0; it < 2; ++it) {
      int chunk = it * 512 + tid;
      int r = chunk >> 5;
      int c = (chunk & 31) ^ (r & 7);
      const ushort_t* src = kbm + (size_t)(kv0 + r) * 256 + c * 8;
      __builtin_amdgcn_global_load_lds((gas_u32)src,
                                       (las_u32)(&lk[bi][0] + chunk * 8), 16, 0, 0);
    }
#pragma unroll
    for (int it = 0; it < 2; ++it) {
      int chunk = it * 512 + tid;
      int r = chunk >> 2;
      int c = (chunk & 3) ^ ((r >> 1) & 3);
      const ushort_t* src = vtb + (size_t)r * S + kv0 + c * 8;
      __builtin_amdgcn_global_load_lds((gas_u32)src,
                                       (las_u32)(&lv[bi][0] + chunk * 8), 16, 0, 0);
    }
  };

  f32x4 mA[2][2], mB[2][2];

  // prologue: stage(0) | mask(0)->mA | stage(1); drain stage(0) only
  stage(0, kvbase);
  __builtin_amdgcn_sched_barrier(0);
#pragma unroll
  for (int qb = 0; qb < 2; ++qb)
#pragma unroll
    for (int kb = 0; kb < 2; ++kb)
      mA[qb][kb] = __builtin_nontemporal_load((const f32x4*)(mrow[qb] + kvbase + kb * 16));
  __builtin_amdgcn_sched_barrier(0);
  stage(1, kvbase + BN);
  __builtin_amdgcn_sched_barrier(0);
  asm volatile("s_waitcnt vmcnt(8)" ::: "memory");
  __builtin_amdgcn_s_barrier();
  __builtin_amdgcn_sched_barrier(0);

  auto body = [&](int t, f32x4 (&mU)[2][2], f32x4 (&mL)[2][2]) {
    const int cur = t % 3;
    const int kvn = kvbase + ((t + 1 < NT) ? (t + 1) : (NT - 1)) * BN;
    const int kvs = kvbase + ((t + 2 < NT) ? (t + 2) : (NT - 1)) * BN;

    // (1) mask(t+1) -> mL  (4 vmem; must precede stage(t+2) in the FIFO)
#pragma unroll
    for (int qb = 0; qb < 2; ++qb)
#pragma unroll
      for (int kb = 0; kb < 2; ++kb)
        mL[qb][kb] = __builtin_nontemporal_load((const f32x4*)(mrow[qb] + kvn + kb * 16));
    __builtin_amdgcn_sched_barrier(0);

    // (2) stage(t+2)  (4 vmem)
    stage((t + 2) % 3, kvs);
    __builtin_amdgcn_sched_barrier(0);

    // (3) QK^T (swapped): sacc[qb][kb] = P^T [key=kb*16+lg*4+r][q=qb*16+lr]
    f32x4 sacc[2][2] = {};
    __builtin_amdgcn_s_setprio(1);
#pragma unroll
    for (int ks = 0; ks < 8; ++ks)
#pragma unroll
      for (int kb = 0; kb < 2; ++kb) {
        int addr = ((kb * 16 + lr) << 9) + ((((ks << 2) + lg) ^ (lr & 7)) << 4);
        bf16x8 kf = *(const bf16x8*)((const char*)&lk[cur][0] + addr);
        sacc[0][kb] = __builtin_amdgcn_mfma_f32_16x16x32_bf16(kf, qf[0][ks], sacc[0][kb], 0, 0, 0);
        sacc[1][kb] = __builtin_amdgcn_mfma_f32_16x16x32_bf16(kf, qf[1][ks], sacc[1][kb], 0, 0, 0);
      }
    __builtin_amdgcn_s_setprio(0);

    // (4) softmax numerator + bf16 pack (uses mU = mask tile t)
    unsigned pw[2][2][2];
#pragma unroll
    for (int qb = 0; qb < 2; ++qb) {
      float p[8];
#pragma unroll
      for (int kb = 0; kb < 2; ++kb)
#pragma unroll
        for (int r = 0; r < 4; ++r) {
          float pv = __builtin_amdgcn_exp2f(sacc[qb][kb][r] * (mU[qb][kb][r] * 0.09016844005556021f));
          p[kb * 4 + r] = pv;
          lsum[qb] += pv;
        }
      pw[qb][0][0] = cvt_pk_bf16(p[0], p[1]);
      pw[qb][0][1] = cvt_pk_bf16(p[2], p[3]);
      pw[qb][1][0] = cvt_pk_bf16(p[4], p[5]);
      pw[qb][1][1] = cvt_pk_bf16(p[6], p[7]);
    }

    // (5) permlane redistribution -> PV B-frag (P[k=lg*8+j][q=lr])
    bf16x8 pfrag[2];
#pragma unroll
    for (int qb = 0; qb < 2; ++qb) {
      unsigned a0 = pw[qb][0][0], a1 = pw[qb][0][1];
      unsigned b0 = pw[qb][1][0], b1 = pw[qb][1][1];
      asm("v_permlane32_swap_b32 %0, %1" : "+v"(a0), "+v"(b0));
      asm("v_permlane16_swap_b32 %0, %1" : "+v"(a0), "+v"(b0));
      asm("v_permlane32_swap_b32 %0, %1" : "+v"(a1), "+v"(b1));
      asm("v_permlane16_swap_b32 %0, %1" : "+v"(a1), "+v"(b1));
      uint4_t u = {a0, a1, b0, b1};
      pfrag[qb] = __builtin_bit_cast(bf16x8, u);
    }

    // (6) PV: O^T[d][q] += V^T[d][k] P^T[k][q]
    __builtin_amdgcn_s_setprio(1);
#pragma unroll
    for (int nd = 0; nd < 16; ++nd) {
      bf16x8 va = *(const bf16x8*)((const char*)&lv[cur][0] + nd * 1024 + lr * 64 + vt_swz);
      oacc[0][nd] = __builtin_amdgcn_mfma_f32_16x16x32_bf16(va, pfrag[0], oacc[0][nd], 0, 0, 0);
      oacc[1][nd] = __builtin_amdgcn_mfma_f32_16x16x32_bf16(va, pfrag[1], oacc[1][nd], 0, 0, 0);
    }
    __builtin_amdgcn_s_setprio(0);

    // (7) drain stage(t+1) (2 bodies old); keep mask(t+1)+stage(t+2) in flight
    asm volatile("s_waitcnt vmcnt(8)" ::: "memory");
    __builtin_amdgcn_s_barrier();
    __builtin_amdgcn_sched_barrier(0);
  };

  for (int t = 0; t < NT; t += 2) {
    body(t, mA, mB);
    body(t + 1, mB, mA);
  }

  // ---- epilogue ----
#pragma unroll
  for (int qb = 0; qb < 2; ++qb) {
    float v = lsum[qb];
    v += __shfl_xor(v, 16);
    v += __shfl_xor(v, 32);
    if (lane < 16)
      lpart[(size_t)split * S + qrow0 + qb * 16 + lr] = v;
#pragma unroll
    for (int nd = 0; nd < 16; ++nd)
      *(f32x4*)(Opart + ((size_t)split * S + qrow0 + qb * 16 + lr) * 256 + nd * 16 + lg * 4) = oacc[qb][nd];
  }
}

// ---------------------------------------------------------------------------
// Combine partials: h[row][d] = sum_s O_s[row][d] / sum_s l_s[row] -> bf16
// grid 2048, block 256; each thread handles 4 elements (one f32x4).
// ---------------------------------------------------------------------------
__global__ __launch_bounds__(256) void combine_kernel(const float* __restrict__ Opart,
                                                      const float* __restrict__ lpart,
                                                      ushort_t* __restrict__ hb) {
  const size_t idx = ((size_t)blockIdx.x * 256 + threadIdx.x) * 4;   // flat over S*256
  const int row = (int)(idx >> 8);
  float L = 0.f;
  f32x4 acc = {};
#pragma unroll
  for (int s2 = 0; s2 < NSPLIT; ++s2) {
    L += lpart[(size_t)s2 * S + row];
    f32x4 v = *(const f32x4*)(Opart + (size_t)s2 * S * 256 + idx);
    acc[0] += v[0]; acc[1] += v[1]; acc[2] += v[2]; acc[3] += v[3];
  }
  const float inv = 1.0f / L;
  ushort4_t p;
  p[0] = f2bf(acc[0] * inv); p[1] = f2bf(acc[1] * inv);
  p[2] = f2bf(acc[2] * inv); p[3] = f2bf(acc[3] * inv);
  *(ushort4_t*)(hb + idx) = p;
}

// ---------------------------------------------------------------------------
extern "C" void kernel_launch(void* const* d_in, const int* in_sizes, int n_in,
                              void* d_out, int out_size, void* d_ws, size_t ws_size,
                              hipStream_t stream) {
  const float* query = (const float*)d_in[0];
  const float* key   = (const float*)d_in[1];
  const float* value = (const float*)d_in[2];
  const float* mask  = (const float*)d_in[3];
  const float* Wq = (const float*)d_in[4];
  const float* bq = (const float*)d_in[5];
  const float* Wk = (const float*)d_in[6];
  const float* bk = (const float*)d_in[7];
  const float* Wv = (const float*)d_in[8];
  const float* bv = (const float*)d_in[9];
  const float* Wo = (const float*)d_in[10];
  const float* bo = (const float*)d_in[11];

  char* ws = (char*)d_ws;
  ushort_t* qb  = (ushort_t*)(ws);                        // 4 MB bf16 [8192,256]
  ushort_t* kb  = (ushort_t*)(ws + ((size_t)4  << 20));   // 4 MB bf16 [8192,256]
  ushort_t* vtb = (ushort_t*)(ws + ((size_t)8  << 20));   // 4 MB bf16 [256,8192]
  ushort_t* hb  = (ushort_t*)(ws + ((size_t)12 << 20));   // 4 MB bf16 [8192,256]
  ushort_t* Wqb = (ushort_t*)(ws + ((size_t)16 << 20));                 // 4x128 KB
  ushort_t* Wkb = (ushort_t*)(ws + ((size_t)16 << 20) + (128u << 10));
  ushort_t* Wvb = (ushort_t*)(ws + ((size_t)16 << 20) + (256u << 10));
  ushort_t* Wob = (ushort_t*)(ws + ((size_t)16 << 20) + (384u << 10));
  float* lpart  = (float*)(ws + ((size_t)16 << 20) + (512u << 10));     // 256 KB
  float* Opart  = (float*)(ws + ((size_t)17 << 20));      // 8 x 8 MB

  wconv_kernel<<<dim3(64, 4), 256, 0, stream>>>(Wq, Wk, Wv, Wo, Wqb, Wkb, Wvb, Wob);

  qkv_kernel<<<dim3(S / 64, 4, 3), 256, 0, stream>>>(query, key, value,
                                                     Wqb, Wkb, Wvb, bq, bk, bv,
                                                     qb, kb, vtb);

  flash_kernel<<<dim3(256), 512, 0, stream>>>(qb, kb, vtb, mask, Opart, lpart);

  combine_kernel<<<dim3(S * 256 / 1024), 256, 0, stream>>>(Opart, lpart, hb);

  oproj_kernel<<<dim3(S / 64, 4), 256, 0, stream>>>(hb, Wob, bo, (float*)d_out);
}

// Round 7
// 226.414 us; speedup vs baseline: 1.9874x; 1.9839x over previous
//
#include <hip/hip_runtime.h>

// ---------------------------------------------------------------------------
// MaskedSelfAttention, S=8192, D=256, multiplicative mask before softmax.
//   q = query@Wq^T+bq ; k = key@Wk^T+bk ; v = value@Wv^T+bv
//   h = softmax(q@k^T * mask * (1/16)) @ v ; out = h@Wo^T + bo
// Round 7: the proven round-3 flash kernel (4 waves x 32 q-rows, 256 thr,
// (256,2), double-buffered K/V, swapped-QK^T + permlane P, vmcnt(4) keeping
// mask in flight) with NSPLIT=8 -> grid 512 = 2 blocks/CU (2x TLP), and
// split-pinned XCD mapping (split = blockIdx & 7 -> K/V L2-resident).
// ---------------------------------------------------------------------------

#define S 8192
#define NSPLIT 8
#define BM 128   // q-rows per block (4 waves x 32)
#define BN 32    // keys per tile
#define KSPL (S / NSPLIT)   // 1024
#define NT (KSPL / BN)      // 32

typedef unsigned short ushort_t;
typedef __attribute__((ext_vector_type(8))) __bf16 bf16x8;
typedef __attribute__((ext_vector_type(4))) float f32x4;
typedef __attribute__((ext_vector_type(4))) ushort_t ushort4_t;
typedef __attribute__((ext_vector_type(8))) ushort_t ushort8_t;
typedef __attribute__((ext_vector_type(4))) unsigned uint4_t;

typedef const __attribute__((address_space(1))) unsigned int* gas_u32;
typedef __attribute__((address_space(3))) unsigned int* las_u32;

__device__ __forceinline__ ushort_t f2bf(float f) {
  unsigned u = __builtin_bit_cast(unsigned, f);
  u += 0x7FFFu + ((u >> 16) & 1u);
  return (ushort_t)(u >> 16);
}

__device__ __forceinline__ bf16x8 pack8(f32x4 a, f32x4 b) {
  ushort8_t u;
  u[0] = f2bf(a[0]); u[1] = f2bf(a[1]); u[2] = f2bf(a[2]); u[3] = f2bf(a[3]);
  u[4] = f2bf(b[0]); u[5] = f2bf(b[1]); u[6] = f2bf(b[2]); u[7] = f2bf(b[3]);
  return __builtin_bit_cast(bf16x8, u);
}

__device__ __forceinline__ unsigned cvt_pk_bf16(float lo, float hi) {
  unsigned r;
  asm("v_cvt_pk_bf16_f32 %0, %1, %2" : "=v"(r) : "v"(lo), "v"(hi));
  return r;
}

// ---------------------------------------------------------------------------
__global__ __launch_bounds__(256) void wconv_kernel(
    const float* __restrict__ w0, const float* __restrict__ w1,
    const float* __restrict__ w2, const float* __restrict__ w3,
    ushort_t* __restrict__ o0, ushort_t* __restrict__ o1,
    ushort_t* __restrict__ o2, ushort_t* __restrict__ o3) {
  const int m = blockIdx.y;
  const float* w = (m == 0) ? w0 : (m == 1) ? w1 : (m == 2) ? w2 : w3;
  ushort_t* o = (m == 0) ? o0 : (m == 1) ? o1 : (m == 2) ? o2 : o3;
  const int idx = (blockIdx.x * 256 + threadIdx.x) * 4;
  f32x4 v = *(const f32x4*)(w + idx);
  ushort4_t p;
  p[0] = f2bf(v[0]); p[1] = f2bf(v[1]); p[2] = f2bf(v[2]); p[3] = f2bf(v[3]);
  *(ushort4_t*)(o + idx) = p;
}

// ---------------------------------------------------------------------------
// Fused QKV projection. grid (128, 4, 3). z==2 writes transposed V^T.
// ---------------------------------------------------------------------------
__global__ __launch_bounds__(256) void qkv_kernel(
    const float* __restrict__ query, const float* __restrict__ key,
    const float* __restrict__ value,
    const ushort_t* __restrict__ Wqb, const ushort_t* __restrict__ Wkb,
    const ushort_t* __restrict__ Wvb,
    const float* __restrict__ bq, const float* __restrict__ bk,
    const float* __restrict__ bv,
    ushort_t* __restrict__ qo, ushort_t* __restrict__ ko,
    ushort_t* __restrict__ vto) {
  __shared__ __align__(16) ushort_t tb[64 * 68];
  const int z = blockIdx.z;
  const float* inp = (z == 0) ? query : (z == 1) ? key : value;
  const ushort_t* Wb = (z == 0) ? Wqb : (z == 1) ? Wkb : Wvb;
  const float* bias = (z == 0) ? bq : (z == 1) ? bk : bv;

  const int tid = threadIdx.x;
  const int lane = tid & 63;
  const int w = tid >> 6;
  const int lr = lane & 15, lg = lane >> 4;
  const int brow0 = blockIdx.x * 64;
  const int row0 = brow0 + w * 16;
  const int col0 = blockIdx.y * 64;

  f32x4 acc[4] = {};
  const int arow = row0 + lr;
  const int kb = lg * 8;

  bf16x8 af[8];
#pragma unroll
  for (int ks = 0; ks < 8; ++ks) {
    const float* ap = inp + (size_t)arow * 256 + ks * 32 + kb;
    af[ks] = pack8(*(const f32x4*)ap, *(const f32x4*)(ap + 4));
  }
#pragma unroll
  for (int ks = 0; ks < 8; ++ks) {
#pragma unroll
    for (int n = 0; n < 4; ++n) {
      bf16x8 bb = *(const bf16x8*)(Wb + (size_t)(col0 + 16 * n + lr) * 256 + ks * 32 + kb);
      acc[n] = __builtin_amdgcn_mfma_f32_16x16x32_bf16(af[ks], bb, acc[n], 0, 0, 0);
    }
  }

  if (z < 2) {
    ushort_t* o = z ? ko : qo;
#pragma unroll
    for (int n = 0; n < 4; ++n) {
      const int col = col0 + 16 * n + lr;
      const float bv_ = bias[col];
      const int rbase = row0 + lg * 4;
#pragma unroll
      for (int r = 0; r < 4; ++r)
        o[(size_t)(rbase + r) * 256 + col] = f2bf(acc[n][r] + bv_);
    }
  } else {
#pragma unroll
    for (int n = 0; n < 4; ++n) {
      const int col = col0 + 16 * n + lr;
      const float bv_ = bias[col];
      const int cl = 16 * n + lr;
      const int rowl = w * 16 + lg * 4;
      ushort4_t pk;
#pragma unroll
      for (int r = 0; r < 4; ++r) pk[r] = f2bf(acc[n][r] + bv_);
      *(ushort4_t*)&tb[cl * 68 + rowl] = pk;
    }
    __syncthreads();
#pragma unroll
    for (int i = 0; i < 4; ++i) {
      int chunk = i * 256 + tid;
      int c = chunk >> 4;
      int off = (chunk & 15) * 4;
      ushort4_t v0 = *(const ushort4_t*)&tb[c * 68 + off];
      *(ushort4_t*)(vto + (size_t)(col0 + c) * S + brow0 + off) = v0;
    }
  }
}

// ---------------------------------------------------------------------------
__global__ __launch_bounds__(256) void oproj_kernel(const ushort_t* __restrict__ inp,
                                                    const ushort_t* __restrict__ Wb,
                                                    const float* __restrict__ bias,
                                                    float* __restrict__ outp) {
  const int tid = threadIdx.x;
  const int lane = tid & 63;
  const int w = tid >> 6;
  const int lr = lane & 15, lg = lane >> 4;
  const int row0 = blockIdx.x * 64 + w * 16;
  const int col0 = blockIdx.y * 64;

  f32x4 acc[4] = {};
  const int arow = row0 + lr;
  const int kb = lg * 8;
#pragma unroll
  for (int ks = 0; ks < 8; ++ks) {
    bf16x8 a = *(const bf16x8*)(inp + (size_t)arow * 256 + ks * 32 + kb);
#pragma unroll
    for (int n = 0; n < 4; ++n) {
      bf16x8 bb = *(const bf16x8*)(Wb + (size_t)(col0 + 16 * n + lr) * 256 + ks * 32 + kb);
      acc[n] = __builtin_amdgcn_mfma_f32_16x16x32_bf16(a, bb, acc[n], 0, 0, 0);
    }
  }
#pragma unroll
  for (int n = 0; n < 4; ++n) {
    const int col = col0 + 16 * n + lr;
    const float bv = bias[col];
    const int rbase = row0 + lg * 4;
#pragma unroll
    for (int r = 0; r < 4; ++r)
      outp[(size_t)(rbase + r) * 256 + col] = acc[n][r] + bv;
  }
}

// ---------------------------------------------------------------------------
// Flash attention core. Grid 512 (1-D), block 256 (4 waves x 32 q-rows).
// split = blockIdx & 7 (pins each K/V split to one XCD -> L2-resident),
// qx = blockIdx >> 3. 2 blocks/CU (LDS 64KB each). Double-buffered K/V;
// stage(t+1) at body top, end-of-body vmcnt(4) drains staging but keeps the
// 4 mask(t+1) loads in flight. Swapped QK^T; P rebuilt in-register via
// cvt_pk_bf16 + permlane{32,16}_swap.
// ---------------------------------------------------------------------------
__global__ __launch_bounds__(256, 2) void flash_kernel(
    const ushort_t* __restrict__ qg, const ushort_t* __restrict__ kbm,
    const ushort_t* __restrict__ vtb, const float* __restrict__ mask,
    float* __restrict__ Opart, float* __restrict__ lpart) {
  __shared__ __align__(16) ushort_t kt[2][BN * 256];   // 2 x 16 KB
  __shared__ __align__(16) ushort_t vt[2][256 * BN];   // 2 x 16 KB

  const int tid = threadIdx.x;
  const int lane = tid & 63;
  const int w = tid >> 6;
  const int lr = lane & 15, lg = lane >> 4;
  const int b = blockIdx.x;
  const int split = b & 7;
  const int qx = b >> 3;
  const int kvbase = split * KSPL;
  const int qrow0 = qx * BM + w * 32;

  // Q fragments (B-operand layout): lane holds Q[q=qb*16+lr][k=ks*32+lg*8+j]
  bf16x8 qf[2][8];
#pragma unroll
  for (int qb = 0; qb < 2; ++qb)
#pragma unroll
    for (int ks = 0; ks < 8; ++ks)
      qf[qb][ks] = *(const bf16x8*)(qg + (size_t)(qrow0 + qb * 16 + lr) * 256 + ks * 32 + lg * 8);

  const float* mrow[2];
#pragma unroll
  for (int qb = 0; qb < 2; ++qb)
    mrow[qb] = mask + (size_t)(qrow0 + qb * 16 + lr) * S + lg * 4;

  f32x4 oacc[2][16] = {};
  float lsum[2] = {0.f, 0.f};
  const int vt_swz = ((lg ^ (lr & 3)) << 4);

  auto stage = [&](int bi, int kv0) {
#pragma unroll
    for (int it = 0; it < 4; ++it) {
      int chunk = it * 256 + (w << 6) + lane;
      int r = chunk >> 5;
      int c = (chunk & 31) ^ (r & 7);
      const ushort_t* src = kbm + (size_t)(kv0 + r) * 256 + c * 8;
      __builtin_amdgcn_global_load_lds((gas_u32)src,
                                       (las_u32)(&kt[bi][0] + it * 2048 + w * 512), 16, 0, 0);
    }
#pragma unroll
    for (int it = 0; it < 4; ++it) {
      int chunk = it * 256 + (w << 6) + lane;
      int r = chunk >> 2;
      int c = (chunk & 3) ^ (r & 3);
      const ushort_t* src = vtb + (size_t)r * S + kv0 + c * 8;
      __builtin_amdgcn_global_load_lds((gas_u32)src,
                                       (las_u32)(&vt[bi][0] + it * 2048 + w * 512), 16, 0, 0);
    }
  };

  f32x4 mcur[2][2];
  auto ld_mask = [&](int kv0) {
#pragma unroll
    for (int qb = 0; qb < 2; ++qb)
#pragma unroll
      for (int kb = 0; kb < 2; ++kb)
        mcur[qb][kb] = __builtin_nontemporal_load((const f32x4*)(mrow[qb] + kv0 + kb * 16));
  };

  // prologue: stage tile 0 (8 loads), mask tile 0 (4 loads); drain staging only
  stage(0, kvbase);
  ld_mask(kvbase);
  asm volatile("s_waitcnt vmcnt(4)" ::: "memory");
  __builtin_amdgcn_s_barrier();
  __builtin_amdgcn_sched_barrier(0);

  for (int t = 0; t < NT; ++t) {
    const int cur = t & 1;
    const int kvn = kvbase + ((t + 1 < NT) ? (t + 1) : t) * BN;

    // (1) staging for t+1 (8 vmem, oldest in queue this iteration)
    stage(cur ^ 1, kvn);

    // (2) QK^T (swapped): sacc[qb][kb] = P^T [key=kb*16+lg*4+r][q=qb*16+lr]
    f32x4 sacc[2][2] = {};
    __builtin_amdgcn_s_setprio(1);
#pragma unroll
    for (int ks = 0; ks < 8; ++ks)
#pragma unroll
      for (int kb = 0; kb < 2; ++kb) {
        int addr = ((kb * 16 + lr) << 9) + ((((ks << 2) + lg) ^ (lr & 7)) << 4);
        bf16x8 kf = *(const bf16x8*)((const char*)&kt[cur][0] + addr);
        sacc[0][kb] = __builtin_amdgcn_mfma_f32_16x16x32_bf16(kf, qf[0][ks], sacc[0][kb], 0, 0, 0);
        sacc[1][kb] = __builtin_amdgcn_mfma_f32_16x16x32_bf16(kf, qf[1][ks], sacc[1][kb], 0, 0, 0);
      }
    __builtin_amdgcn_s_setprio(0);

    // (3) softmax numerator + bf16 pack: p = exp2(s * mask * SCALE*log2e)
    unsigned pw[2][2][2];
#pragma unroll
    for (int qb = 0; qb < 2; ++qb) {
      float p[8];
#pragma unroll
      for (int kb = 0; kb < 2; ++kb)
#pragma unroll
        for (int r = 0; r < 4; ++r) {
          float pv = __builtin_amdgcn_exp2f(sacc[qb][kb][r] * (mcur[qb][kb][r] * 0.09016844005556021f));
          p[kb * 4 + r] = pv;
          lsum[qb] += pv;
        }
      pw[qb][0][0] = cvt_pk_bf16(p[0], p[1]);
      pw[qb][0][1] = cvt_pk_bf16(p[2], p[3]);
      pw[qb][1][0] = cvt_pk_bf16(p[4], p[5]);
      pw[qb][1][1] = cvt_pk_bf16(p[6], p[7]);
    }

    // (4) mask prefetch for t+1 (4 vmem, newest; survives the barrier)
    ld_mask(kvn);

    // (5) permlane redistribution -> PV B-frag (P[k=lg*8+j][q=lr])
    bf16x8 pfrag[2];
#pragma unroll
    for (int qb = 0; qb < 2; ++qb) {
      unsigned a0 = pw[qb][0][0], a1 = pw[qb][0][1];
      unsigned b0 = pw[qb][1][0], b1 = pw[qb][1][1];
      asm("v_permlane32_swap_b32 %0, %1" : "+v"(a0), "+v"(b0));
      asm("v_permlane16_swap_b32 %0, %1" : "+v"(a0), "+v"(b0));
      asm("v_permlane32_swap_b32 %0, %1" : "+v"(a1), "+v"(b1));
      asm("v_permlane16_swap_b32 %0, %1" : "+v"(a1), "+v"(b1));
      uint4_t u = {a0, a1, b0, b1};
      pfrag[qb] = __builtin_bit_cast(bf16x8, u);
    }

    // (6) PV: O^T[d][q] += V^T[d][k] P^T[k][q]
    __builtin_amdgcn_s_setprio(1);
#pragma unroll
    for (int nd = 0; nd < 16; ++nd) {
      bf16x8 va = *(const bf16x8*)((const char*)&vt[cur][0] + nd * 1024 + lr * 64 + vt_swz);
      oacc[0][nd] = __builtin_amdgcn_mfma_f32_16x16x32_bf16(va, pfrag[0], oacc[0][nd], 0, 0, 0);
      oacc[1][nd] = __builtin_amdgcn_mfma_f32_16x16x32_bf16(va, pfrag[1], oacc[1][nd], 0, 0, 0);
    }
    __builtin_amdgcn_s_setprio(0);

    // (7) drain stage(t+1); keep the 4 mask(t+1) loads in flight
    asm volatile("s_waitcnt vmcnt(4)" ::: "memory");
    __builtin_amdgcn_s_barrier();
    __builtin_amdgcn_sched_barrier(0);
  }

  // ---- epilogue ----
#pragma unroll
  for (int qb = 0; qb < 2; ++qb) {
    float v = lsum[qb];
    v += __shfl_xor(v, 16);
    v += __shfl_xor(v, 32);
    if (lane < 16)
      lpart[(size_t)split * S + qrow0 + qb * 16 + lr] = v;
#pragma unroll
    for (int nd = 0; nd < 16; ++nd)
      *(f32x4*)(Opart + ((size_t)split * S + qrow0 + qb * 16 + lr) * 256 + nd * 16 + lg * 4) = oacc[qb][nd];
  }
}

// ---------------------------------------------------------------------------
// Combine partials: h[row][d] = sum_s O_s[row][d] / sum_s l_s[row] -> bf16
// grid 2048, block 256; each thread one f32x4.
// ---------------------------------------------------------------------------
__global__ __launch_bounds__(256) void combine_kernel(const float* __restrict__ Opart,
                                                      const float* __restrict__ lpart,
                                                      ushort_t* __restrict__ hb) {
  const size_t idx = ((size_t)blockIdx.x * 256 + threadIdx.x) * 4;   // flat over S*256
  const int row = (int)(idx >> 8);
  float L = 0.f;
  f32x4 acc = {};
#pragma unroll
  for (int s2 = 0; s2 < NSPLIT; ++s2) {
    L += lpart[(size_t)s2 * S + row];
    f32x4 v = *(const f32x4*)(Opart + (size_t)s2 * S * 256 + idx);
    acc[0] += v[0]; acc[1] += v[1]; acc[2] += v[2]; acc[3] += v[3];
  }
  const float inv = 1.0f / L;
  ushort4_t p;
  p[0] = f2bf(acc[0] * inv); p[1] = f2bf(acc[1] * inv);
  p[2] = f2bf(acc[2] * inv); p[3] = f2bf(acc[3] * inv);
  *(ushort4_t*)(hb + idx) = p;
}

// ---------------------------------------------------------------------------
extern "C" void kernel_launch(void* const* d_in, const int* in_sizes, int n_in,
                              void* d_out, int out_size, void* d_ws, size_t ws_size,
                              hipStream_t stream) {
  const float* query = (const float*)d_in[0];
  const float* key   = (const float*)d_in[1];
  const float* value = (const float*)d_in[2];
  const float* mask  = (const float*)d_in[3];
  const float* Wq = (const float*)d_in[4];
  const float* bq = (const float*)d_in[5];
  const float* Wk = (const float*)d_in[6];
  const float* bk = (const float*)d_in[7];
  const float* Wv = (const float*)d_in[8];
  const float* bv = (const float*)d_in[9];
  const float* Wo = (const float*)d_in[10];
  const float* bo = (const float*)d_in[11];

  char* ws = (char*)d_ws;
  ushort_t* qb  = (ushort_t*)(ws);                        // 4 MB bf16 [8192,256]
  ushort_t* kb  = (ushort_t*)(ws + ((size_t)4  << 20));   // 4 MB bf16 [8192,256]
  ushort_t* vtb = (ushort_t*)(ws + ((size_t)8  << 20));   // 4 MB bf16 [256,8192]
  ushort_t* hb  = (ushort_t*)(ws + ((size_t)12 << 20));   // 4 MB bf16 [8192,256]
  ushort_t* Wqb = (ushort_t*)(ws + ((size_t)16 << 20));                 // 4x128 KB
  ushort_t* Wkb = (ushort_t*)(ws + ((size_t)16 << 20) + (128u << 10));
  ushort_t* Wvb = (ushort_t*)(ws + ((size_t)16 << 20) + (256u << 10));
  ushort_t* Wob = (ushort_t*)(ws + ((size_t)16 << 20) + (384u << 10));
  float* lpart  = (float*)(ws + ((size_t)16 << 20) + (512u << 10));     // 256 KB
  float* Opart  = (float*)(ws + ((size_t)17 << 20));      // 8 x 8 MB

  wconv_kernel<<<dim3(64, 4), 256, 0, stream>>>(Wq, Wk, Wv, Wo, Wqb, Wkb, Wvb, Wob);

  qkv_kernel<<<dim3(S / 64, 4, 3), 256, 0, stream>>>(query, key, value,
                                                     Wqb, Wkb, Wvb, bq, bk, bv,
                                                     qb, kb, vtb);

  flash_kernel<<<dim3(512), 256, 0, stream>>>(qb, kb, vtb, mask, Opart, lpart);

  combine_kernel<<<dim3(S * 256 / 1024), 256, 0, stream>>>(Opart, lpart, hb);

  oproj_kernel<<<dim3(S / 64, 4), 256, 0, stream>>>(hb, Wob, bo, (float*)d_out);
}